// Round 7
// baseline (557.253 us; speedup 1.0000x reference)
//
#include <hip/hip_runtime.h>
#include <stdint.h>

#define N_NODES 4096
#define F_DIM   256
#define BATCH   8

typedef __attribute__((ext_vector_type(8))) __bf16 bf16x8;
typedef __attribute__((ext_vector_type(4))) float  f32x4;
typedef __attribute__((ext_vector_type(8))) unsigned short u16x8;

typedef const __attribute__((address_space(1))) void* gas1_t;
typedef __attribute__((address_space(3))) void*       las3_t;

__device__ __forceinline__ void stage16(const void* g, void* l) {
  __builtin_amdgcn_global_load_lds((gas1_t)g, (las3_t)l, 16, 0, 0);
}

__device__ __forceinline__ unsigned short f2bf(float f) {
  union { float f; uint32_t u; } v; v.f = f;
  uint32_t u = v.u;
  return (unsigned short)((u + 0x7FFFu + ((u >> 16) & 1u)) >> 16); // RTNE
}
__device__ __forceinline__ float bf2f(unsigned short u) {
  union { uint32_t u; float f; } v; v.u = ((uint32_t)u) << 16;
  return v.f;
}

// ---------------- k_pre: fused H/W bf16 casts + symmetrize+degree ----------------
__global__ __launch_bounds__(256) void k_pre(const float* __restrict__ A,
                                             unsigned short* __restrict__ Sb,
                                             float* __restrict__ D,
                                             const float4* __restrict__ H4,
                                             ushort4* __restrict__ Hb4,
                                             const float* __restrict__ W,
                                             unsigned short* __restrict__ Wt) {
  int t = threadIdx.x;
  int bid = blockIdx.y * 64 + blockIdx.x;
  {
    int i = bid * 512 + t;
    float4 v = H4[i];
    ushort4 o; o.x = f2bf(v.x); o.y = f2bf(v.y); o.z = f2bf(v.z); o.w = f2bf(v.w);
    Hb4[i] = o;
    i += 256;
    v = H4[i];
    o.x = f2bf(v.x); o.y = f2bf(v.y); o.z = f2bf(v.z); o.w = f2bf(v.w);
    Hb4[i] = o;
  }
  if (bid < 256) Wt[t * 256 + bid] = f2bf(W[bid * 256 + t]);

  int bi = blockIdx.y, bj = blockIdx.x;
  if (bj < bi) return;
  __shared__ float L1[64][65];
  __shared__ float L2[64][65];
  __shared__ float Pr[4][64];
  __shared__ float Pc[4][64];
  int i0 = bi * 64, j0 = bj * 64;
  for (int it = 0; it < 16; ++it) {
    int idx = it * 256 + t;
    int r = idx >> 6, c = idx & 63;
    L1[r][c] = A[(size_t)(i0 + r) * N_NODES + (j0 + c)];
    L2[c][r] = A[(size_t)(j0 + r) * N_NODES + (i0 + c)];
  }
  __syncthreads();
  float colsum = 0.f;
  int cfix = t & 63, q = t >> 6;
  for (int it = 0; it < 16; ++it) {
    int r = it * 4 + q;
    float v = 0.5f * (L1[r][cfix] + L2[r][cfix]);
    v = v > 0.f ? v : 0.f;
    Sb[(size_t)(i0 + r) * N_NODES + (j0 + cfix)] = f2bf(v);
    colsum += v;
    L1[r][cfix] = v;
  }
  Pc[q][cfix] = colsum;
  __syncthreads();
  {
    int r = t & 63, seg = t >> 6;
    float s = 0.f;
    for (int c = seg * 16; c < seg * 16 + 16; ++c) s += L1[r][c];
    Pr[seg][r] = s;
  }
  __syncthreads();
  if (t < 64) {
    float d = Pr[0][t] + Pr[1][t] + Pr[2][t] + Pr[3][t];
    atomicAdd(&D[i0 + t], d);
  } else if (t < 128 && bi != bj) {
    int c = t - 64;
    float d = Pc[0][c] + Pc[1][c] + Pc[2][c] + Pc[3][c];
    atomicAdd(&D[j0 + c], d);
  }
  if (bi != bj) {
    for (int it = 0; it < 16; ++it) {
      int idx = it * 256 + t;
      int ro = idx >> 6, co = idx & 63;
      Sb[(size_t)(j0 + ro) * N_NODES + (i0 + co)] = f2bf(L1[co][ro]);
    }
  }
}

__global__ void k_dinv(const float* __restrict__ D, float* __restrict__ dinv) {
  int i = blockIdx.x * blockDim.x + threadIdx.x;
  if (i < N_NODES) {
    float d = D[i];
    dinv[i] = d > 0.f ? 1.0f / sqrtf(d) : 0.f;
  }
}

// ---------------- GEMM1: HW = Hb @ Wt^T; HWb (bf16) + Gt[b*256+o][n]=dinv[n]*HW ----
__global__ __launch_bounds__(256) void k_gemm1(const unsigned short* __restrict__ Hb,
                                               const unsigned short* __restrict__ Wt,
                                               const float* __restrict__ dinv,
                                               unsigned short* __restrict__ HWb,
                                               unsigned short* __restrict__ Gt) {
  __shared__ __align__(16) unsigned short As[128 * 32];
  __shared__ __align__(16) unsigned short Bs[128 * 32];
  __shared__ __align__(16) unsigned short T[128][136];
  int t = threadIdx.x;
  int lane = t & 63;
  int q = lane >> 4, r16 = lane & 15;
  int wave = t >> 6;
  int wm = wave >> 1, wn = wave & 1;
  int m0 = blockIdx.y * 128;
  int o0 = blockIdx.x * 128;
  const int K = 256;

  const unsigned short* Abase = Hb + (size_t)m0 * K;
  const unsigned short* Bbase = Wt + (size_t)o0 * K;

  f32x4 acc[4][4];
#pragma unroll
  for (int i = 0; i < 4; ++i)
#pragma unroll
    for (int j = 0; j < 4; ++j) acc[i][j] = f32x4{0.f, 0.f, 0.f, 0.f};

  int idx0 = t, idx1 = 256 + t;
  int wb0 = (t & ~63) * 8;
  int wb1 = (256 + (t & ~63)) * 8;

  for (int kt = 0; kt < K / 32; ++kt) {
    int kof = kt * 32;
    stage16(Abase + (size_t)(idx0 >> 2) * K + kof + ((idx0 & 3) << 3), &As[wb0]);
    stage16(Abase + (size_t)(idx1 >> 2) * K + kof + ((idx1 & 3) << 3), &As[wb1]);
    stage16(Bbase + (size_t)(idx0 >> 2) * K + kof + ((idx0 & 3) << 3), &Bs[wb0]);
    stage16(Bbase + (size_t)(idx1 >> 2) * K + kof + ((idx1 & 3) << 3), &Bs[wb1]);
    __syncthreads();
    bf16x8 a[4], b[4];
#pragma unroll
    for (int mi = 0; mi < 4; ++mi)
      a[mi] = *(const bf16x8*)&As[(wm * 64 + mi * 16 + r16) * 32 + q * 8];
#pragma unroll
    for (int ni = 0; ni < 4; ++ni)
      b[ni] = *(const bf16x8*)&Bs[(wn * 64 + ni * 16 + r16) * 32 + q * 8];
#pragma unroll
    for (int mi = 0; mi < 4; ++mi)
#pragma unroll
      for (int ni = 0; ni < 4; ++ni)
        acc[mi][ni] = __builtin_amdgcn_mfma_f32_16x16x32_bf16(a[mi], b[ni], acc[mi][ni], 0, 0, 0);
    __syncthreads();
  }

#pragma unroll
  for (int mi = 0; mi < 4; ++mi) {
    int row = wm * 64 + mi * 16 + q * 4;
#pragma unroll
    for (int ni = 0; ni < 4; ++ni) {
      int col = wn * 64 + ni * 16 + r16;
#pragma unroll
      for (int rr = 0; rr < 4; ++rr) {
        unsigned short h = f2bf(acc[mi][ni][rr]);
        HWb[(size_t)(m0 + row + rr) * F_DIM + (o0 + col)] = h;
        T[col][row + rr] = h;
      }
    }
  }
  __syncthreads();
  int b = m0 >> 12, n0 = m0 & 4095;
  for (int it = 0; it < 8; ++it) {
    int unit = it * 256 + t;
    int ro = unit >> 4;
    int cs = (unit & 15) * 8;
    u16x8 v = *(const u16x8*)&T[ro][cs];
    u16x8 w;
#pragma unroll
    for (int j = 0; j < 8; ++j)
      w[j] = f2bf(bf2f(v[j]) * dinv[n0 + cs + j]);
    *(u16x8*)&Gt[(size_t)(b * 256 + o0 + ro) * N_NODES + n0 + cs] = w;
  }
}

// ---------------- GEMM2: BK=64 double-buffered LDS, early prefetch (stage(kt+1)
// issued before MFMA(kt) so the vmcnt drain at the next barrier has a full
// compute block in flight), kz-parity split, unit-rotation swizzle
// (u' = (u+row)&7: 8 consecutive lanes hit 8 distinct 16B units = 32 banks),
// XCD patch swizzle, chunked cross-kz reduction, fused epilogue. ----------------
__global__ __launch_bounds__(256, 2) void k_gemm2(const unsigned short* __restrict__ Sb,
                                                  const unsigned short* __restrict__ Gt,
                                                  const unsigned short* __restrict__ HWb,
                                                  const float* __restrict__ dinv,
                                                  float* __restrict__ Out) {
  __shared__ __align__(16) unsigned short As[2][128 * 64];  // 2 x 16 KB
  __shared__ __align__(16) unsigned short Bs[2][128 * 64];  // 2 x 16 KB
  __shared__ float Red[16 * 132];                           // 8.4 KB
  const int K = N_NODES;
  const int KT = K / 64;   // 64
  int t = threadIdx.x;
  int lane = t & 63;
  int q = lane >> 4, r16 = lane & 15;
  int wave = t >> 6;
  int wm = wave >> 1;      // m-half
  int kz = wave & 1;       // kt parity this wave computes

  // XCD patch swizzle: 512 blocks; bid%8 -> XCD; each XCD an 8x8 tile patch
  int bid = blockIdx.y * 16 + blockIdx.x;
  int patch = bid & 7;
  int local = bid >> 3;
  int mt = (patch >> 1) * 8 + (local & 7);
  int nt = (patch & 1) * 8 + (local >> 3);
  int m0 = mt * 128;
  int n0 = nt * 128;

  const unsigned short* Abase = Sb + (size_t)m0 * K;
  const unsigned short* Bbase = Gt + (size_t)n0 * K;

  f32x4 acc[4][8];
#pragma unroll
  for (int i = 0; i < 4; ++i)
#pragma unroll
    for (int j = 0; j < 8; ++j) acc[i][j] = f32x4{0.f, 0.f, 0.f, 0.f};

  // staging: 1024 16B-units per matrix per kt; thread handles units t+j*256.
  // unit s: row = s>>3, u' = s&7 (LDS slot), source u = (u'-row)&7.
  size_t gsrc[4];
  int ldsu[4];
#pragma unroll
  for (int j = 0; j < 4; ++j) {
    int s = j * 256 + t;
    int row = s >> 3, up = s & 7;
    int u = (up - row) & 7;
    gsrc[j] = (size_t)row * K + u * 8;
    ldsu[j] = (j * 256 + (t & ~63)) * 8;   // wave-uniform LDS elem base
  }

  // frag read offsets (elements): row*64 + ((c*4+q+row)&7)*8
  int aoff[2][4], boff[2][8];
#pragma unroll
  for (int c = 0; c < 2; ++c) {
#pragma unroll
    for (int mi = 0; mi < 4; ++mi) {
      int row = wm * 64 + mi * 16 + r16;
      aoff[c][mi] = row * 64 + (((c * 4 + q + row) & 7) << 3);
    }
#pragma unroll
    for (int ni = 0; ni < 8; ++ni) {
      int row = ni * 16 + r16;
      boff[c][ni] = row * 64 + (((c * 4 + q + row) & 7) << 3);
    }
  }

#define STG(kt, bb)                                              \
  {                                                              \
    size_t kof = (size_t)(kt) * 64;                              \
    _Pragma("unroll")                                            \
    for (int j = 0; j < 4; ++j) {                                \
      stage16(Abase + gsrc[j] + kof, &As[bb][ldsu[j]]);          \
      stage16(Bbase + gsrc[j] + kof, &Bs[bb][ldsu[j]]);          \
    }                                                            \
  }

  STG(0, 0)
  for (int kt = 0; kt < KT; ++kt) {
    int cur = kt & 1;
    __syncthreads();                       // drains stage(kt) (one compute block old)
    if (kt + 1 < KT) STG(kt + 1, cur ^ 1)  // in flight across MFMA below
    if ((kt & 1) == kz) {
#pragma unroll
      for (int c = 0; c < 2; ++c) {
        bf16x8 a[4], b[8];
#pragma unroll
        for (int mi = 0; mi < 4; ++mi) a[mi] = *(const bf16x8*)&As[cur][aoff[c][mi]];
#pragma unroll
        for (int ni = 0; ni < 8; ++ni) b[ni] = *(const bf16x8*)&Bs[cur][boff[c][ni]];
#pragma unroll
        for (int mi = 0; mi < 4; ++mi)
#pragma unroll
          for (int ni = 0; ni < 8; ++ni)
            acc[mi][ni] = __builtin_amdgcn_mfma_f32_16x16x32_bf16(a[mi], b[ni], acc[mi][ni], 0, 0, 0);
      }
    }
  }
#undef STG

  // chunked cross-kz reduction + fused epilogue: 8 rounds of 16 rows
  for (int round = 0; round < 8; ++round) {
    int half = round >> 2, mi = round & 3;
    if (wm == half && kz == 1) {
#pragma unroll
      for (int ni = 0; ni < 8; ++ni)
#pragma unroll
        for (int rr = 0; rr < 4; ++rr)
          Red[(q * 4 + rr) * 132 + ni * 16 + r16] = acc[mi][ni][rr];
    }
    __syncthreads();
    if (wm == half && kz == 0) {
      int row = m0 + wm * 64 + mi * 16 + q * 4;
      float di[4];
#pragma unroll
      for (int rr = 0; rr < 4; ++rr) di[rr] = dinv[row + rr];
#pragma unroll
      for (int ni = 0; ni < 8; ++ni) {
        int col = n0 + ni * 16 + r16;
        int b_ = col >> 8, o = col & 255;
#pragma unroll
        for (int rr = 0; rr < 4; ++rr) {
          float v = acc[mi][ni][rr] + Red[(q * 4 + rr) * 132 + ni * 16 + r16];
          size_t oi = ((size_t)b_ * N_NODES + (row + rr)) * F_DIM + o;
          float u = bf2f(HWb[oi]) - di[rr] * v;
          Out[oi] = u > 0.f ? u : 0.f;
        }
      }
    }
    __syncthreads();
  }
}

extern "C" void kernel_launch(void* const* d_in, const int* in_sizes, int n_in,
                              void* d_out, int out_size, void* d_ws, size_t ws_size,
                              hipStream_t stream) {
  (void)in_sizes; (void)n_in; (void)out_size; (void)ws_size;
  const float* H = (const float*)d_in[0];
  const float* W = (const float*)d_in[1];
  const float* A = (const float*)d_in[2];
  float* out = (float*)d_out;

  char* ws = (char*)d_ws;
  size_t off = 0;
  auto alloc = [&](size_t bytes) {
    char* p = ws + off;
    off += (bytes + 255) & ~(size_t)255;
    return p;
  };
  float*          Dd   = (float*)alloc((size_t)N_NODES * 4);
  float*          dinv = (float*)alloc((size_t)N_NODES * 4);
  unsigned short* Sb   = (unsigned short*)alloc((size_t)N_NODES * N_NODES * 2);        // 32 MB
  unsigned short* HWb  = (unsigned short*)alloc((size_t)BATCH * N_NODES * F_DIM * 2);  // 16 MB
  unsigned short* Gt   = (unsigned short*)alloc((size_t)BATCH * F_DIM * N_NODES * 2);  // 16 MB
  unsigned short* Wt   = (unsigned short*)alloc((size_t)F_DIM * F_DIM * 2);
  unsigned short* Hb   = (unsigned short*)alloc((size_t)BATCH * N_NODES * F_DIM * 2);  // 16 MB

  hipMemsetAsync(Dd, 0, N_NODES * 4, stream);
  k_pre<<<dim3(64, 64), 256, 0, stream>>>(A, Sb, Dd, (const float4*)H, (ushort4*)Hb, W, Wt);
  k_dinv<<<16, 256, 0, stream>>>(Dd, dinv);
  k_gemm1<<<dim3(2, 256), 256, 0, stream>>>(Hb, Wt, dinv, HWb, Gt);
  k_gemm2<<<dim3(16, 32), 256, 0, stream>>>(Sb, Gt, HWb, dinv, out);
}

// Round 8
// 260.670 us; speedup vs baseline: 2.1378x; 2.1378x over previous
//
#include <hip/hip_runtime.h>
#include <stdint.h>

#define N_NODES 4096
#define F_DIM   256
#define BATCH   8

typedef __attribute__((ext_vector_type(8))) __bf16 bf16x8;
typedef __attribute__((ext_vector_type(4))) float  f32x4;
typedef __attribute__((ext_vector_type(8))) unsigned short u16x8;

typedef const __attribute__((address_space(1))) void* gas1_t;
typedef __attribute__((address_space(3))) void*       las3_t;

__device__ __forceinline__ void stage16(const void* g, void* l) {
  __builtin_amdgcn_global_load_lds((gas1_t)g, (las3_t)l, 16, 0, 0);
}

__device__ __forceinline__ unsigned short f2bf(float f) {
  union { float f; uint32_t u; } v; v.f = f;
  uint32_t u = v.u;
  return (unsigned short)((u + 0x7FFFu + ((u >> 16) & 1u)) >> 16); // RTNE
}
__device__ __forceinline__ float bf2f(unsigned short u) {
  union { uint32_t u; float f; } v; v.u = ((uint32_t)u) << 16;
  return v.f;
}

// ---------------- k_pre: fused H/W bf16 casts + symmetrize+degree ----------------
__global__ __launch_bounds__(256) void k_pre(const float* __restrict__ A,
                                             unsigned short* __restrict__ Sb,
                                             float* __restrict__ D,
                                             const float4* __restrict__ H4,
                                             ushort4* __restrict__ Hb4,
                                             const float* __restrict__ W,
                                             unsigned short* __restrict__ Wt) {
  int t = threadIdx.x;
  int bid = blockIdx.y * 64 + blockIdx.x;
  {
    int i = bid * 512 + t;
    float4 v = H4[i];
    ushort4 o; o.x = f2bf(v.x); o.y = f2bf(v.y); o.z = f2bf(v.z); o.w = f2bf(v.w);
    Hb4[i] = o;
    i += 256;
    v = H4[i];
    o.x = f2bf(v.x); o.y = f2bf(v.y); o.z = f2bf(v.z); o.w = f2bf(v.w);
    Hb4[i] = o;
  }
  if (bid < 256) Wt[t * 256 + bid] = f2bf(W[bid * 256 + t]);

  int bi = blockIdx.y, bj = blockIdx.x;
  if (bj < bi) return;
  __shared__ float L1[64][65];
  __shared__ float L2[64][65];
  __shared__ float Pr[4][64];
  __shared__ float Pc[4][64];
  int i0 = bi * 64, j0 = bj * 64;
  for (int it = 0; it < 16; ++it) {
    int idx = it * 256 + t;
    int r = idx >> 6, c = idx & 63;
    L1[r][c] = A[(size_t)(i0 + r) * N_NODES + (j0 + c)];
    L2[c][r] = A[(size_t)(j0 + r) * N_NODES + (i0 + c)];
  }
  __syncthreads();
  float colsum = 0.f;
  int cfix = t & 63, q = t >> 6;
  for (int it = 0; it < 16; ++it) {
    int r = it * 4 + q;
    float v = 0.5f * (L1[r][cfix] + L2[r][cfix]);
    v = v > 0.f ? v : 0.f;
    Sb[(size_t)(i0 + r) * N_NODES + (j0 + cfix)] = f2bf(v);
    colsum += v;
    L1[r][cfix] = v;
  }
  Pc[q][cfix] = colsum;
  __syncthreads();
  {
    int r = t & 63, seg = t >> 6;
    float s = 0.f;
    for (int c = seg * 16; c < seg * 16 + 16; ++c) s += L1[r][c];
    Pr[seg][r] = s;
  }
  __syncthreads();
  if (t < 64) {
    float d = Pr[0][t] + Pr[1][t] + Pr[2][t] + Pr[3][t];
    atomicAdd(&D[i0 + t], d);
  } else if (t < 128 && bi != bj) {
    int c = t - 64;
    float d = Pc[0][c] + Pc[1][c] + Pc[2][c] + Pc[3][c];
    atomicAdd(&D[j0 + c], d);
  }
  if (bi != bj) {
    for (int it = 0; it < 16; ++it) {
      int idx = it * 256 + t;
      int ro = idx >> 6, co = idx & 63;
      Sb[(size_t)(j0 + ro) * N_NODES + (i0 + co)] = f2bf(L1[co][ro]);
    }
  }
}

__global__ void k_dinv(const float* __restrict__ D, float* __restrict__ dinv) {
  int i = blockIdx.x * blockDim.x + threadIdx.x;
  if (i < N_NODES) {
    float d = D[i];
    dinv[i] = d > 0.f ? 1.0f / sqrtf(d) : 0.f;
  }
}

// ---------------- GEMM1: HW = Hb @ Wt^T; HWb (bf16) + Gt[b*256+o][n]=dinv[n]*HW ----
__global__ __launch_bounds__(256) void k_gemm1(const unsigned short* __restrict__ Hb,
                                               const unsigned short* __restrict__ Wt,
                                               const float* __restrict__ dinv,
                                               unsigned short* __restrict__ HWb,
                                               unsigned short* __restrict__ Gt) {
  __shared__ __align__(16) unsigned short As[128 * 32];
  __shared__ __align__(16) unsigned short Bs[128 * 32];
  __shared__ __align__(16) unsigned short T[128][136];
  int t = threadIdx.x;
  int lane = t & 63;
  int q = lane >> 4, r16 = lane & 15;
  int wave = t >> 6;
  int wm = wave >> 1, wn = wave & 1;
  int m0 = blockIdx.y * 128;
  int o0 = blockIdx.x * 128;
  const int K = 256;

  const unsigned short* Abase = Hb + (size_t)m0 * K;
  const unsigned short* Bbase = Wt + (size_t)o0 * K;

  f32x4 acc[4][4];
#pragma unroll
  for (int i = 0; i < 4; ++i)
#pragma unroll
    for (int j = 0; j < 4; ++j) acc[i][j] = f32x4{0.f, 0.f, 0.f, 0.f};

  int idx0 = t, idx1 = 256 + t;
  int wb0 = (t & ~63) * 8;
  int wb1 = (256 + (t & ~63)) * 8;

  for (int kt = 0; kt < K / 32; ++kt) {
    int kof = kt * 32;
    stage16(Abase + (size_t)(idx0 >> 2) * K + kof + ((idx0 & 3) << 3), &As[wb0]);
    stage16(Abase + (size_t)(idx1 >> 2) * K + kof + ((idx1 & 3) << 3), &As[wb1]);
    stage16(Bbase + (size_t)(idx0 >> 2) * K + kof + ((idx0 & 3) << 3), &Bs[wb0]);
    stage16(Bbase + (size_t)(idx1 >> 2) * K + kof + ((idx1 & 3) << 3), &Bs[wb1]);
    __syncthreads();
    bf16x8 a[4], b[4];
#pragma unroll
    for (int mi = 0; mi < 4; ++mi)
      a[mi] = *(const bf16x8*)&As[(wm * 64 + mi * 16 + r16) * 32 + q * 8];
#pragma unroll
    for (int ni = 0; ni < 4; ++ni)
      b[ni] = *(const bf16x8*)&Bs[(wn * 64 + ni * 16 + r16) * 32 + q * 8];
#pragma unroll
    for (int mi = 0; mi < 4; ++mi)
#pragma unroll
      for (int ni = 0; ni < 4; ++ni)
        acc[mi][ni] = __builtin_amdgcn_mfma_f32_16x16x32_bf16(a[mi], b[ni], acc[mi][ni], 0, 0, 0);
    __syncthreads();
  }

#pragma unroll
  for (int mi = 0; mi < 4; ++mi) {
    int row = wm * 64 + mi * 16 + q * 4;
#pragma unroll
    for (int ni = 0; ni < 4; ++ni) {
      int col = wn * 64 + ni * 16 + r16;
#pragma unroll
      for (int rr = 0; rr < 4; ++rr) {
        unsigned short h = f2bf(acc[mi][ni][rr]);
        HWb[(size_t)(m0 + row + rr) * F_DIM + (o0 + col)] = h;
        T[col][row + rr] = h;
      }
    }
  }
  __syncthreads();
  int b = m0 >> 12, n0 = m0 & 4095;
  for (int it = 0; it < 8; ++it) {
    int unit = it * 256 + t;
    int ro = unit >> 4;
    int cs = (unit & 15) * 8;
    u16x8 v = *(const u16x8*)&T[ro][cs];
    u16x8 w;
#pragma unroll
    for (int j = 0; j < 8; ++j)
      w[j] = f2bf(bf2f(v[j]) * dinv[n0 + cs + j]);
    *(u16x8*)&Gt[(size_t)(b * 256 + o0 + ro) * N_NODES + n0 + cs] = w;
  }
}

// ---------------- GEMM2: 128-thread / 2-wave blocks, 128x64 tile (64x64/wave),
// BK=32 single-buffer m97 loop, round-5 conflict swizzle, grid 1024 =
// 4 blocks/CU (8 waves/CU all MFMA-active; barriers couple only 2 waves).
// XCD patch: each XCD owns 4mt x 32nt. Fused epilogue. ----------------
__global__ __launch_bounds__(128) void k_gemm2(const unsigned short* __restrict__ Sb,
                                               const unsigned short* __restrict__ Gt,
                                               const unsigned short* __restrict__ HWb,
                                               const float* __restrict__ dinv,
                                               float* __restrict__ Out) {
  __shared__ __align__(16) unsigned short As[128 * 32];  // 8 KB
  __shared__ __align__(16) unsigned short Bs[64 * 32];   // 4 KB
  const int K = N_NODES;
  int t = threadIdx.x;
  int lane = t & 63;
  int q = lane >> 4, r16 = lane & 15;
  int wm = t >> 6;   // wave id: m-half of the 128-row tile

  // XCD patch swizzle: 1024 blocks; bid%8 -> XCD; each XCD 4mt x 32nt
  int bid = blockIdx.x;
  int xcd = bid & 7;
  int local = bid >> 3;          // 0..127
  int mt = xcd * 4 + (local >> 5);   // 0..31
  int nt = local & 31;               // 0..31
  int m0 = mt * 128;
  int n0 = nt * 64;

  const unsigned short* Abase = Sb + (size_t)m0 * K;
  const unsigned short* Bbase = Gt + (size_t)n0 * K;

  f32x4 acc[4][4];
#pragma unroll
  for (int i = 0; i < 4; ++i)
#pragma unroll
    for (int j = 0; j < 4; ++j) acc[i][j] = f32x4{0.f, 0.f, 0.f, 0.f};

  // staging: A = 512 16B-units (4 calls), B = 256 units (2 calls).
  // unit u: row=u>>2, slot qs=u&3, source q=((qs)-(row>>1))&3.
  size_t ga[4], gb[2];
  int la[4], lb[2];
#pragma unroll
  for (int j = 0; j < 4; ++j) {
    int u = j * 128 + t;
    int r = u >> 2, qq = ((u & 3) - (r >> 1)) & 3;
    ga[j] = (size_t)r * K + qq * 8;
    la[j] = (j * 128 + (t & ~63)) * 8;
  }
#pragma unroll
  for (int j = 0; j < 2; ++j) {
    int u = j * 128 + t;
    int r = u >> 2, qq = ((u & 3) - (r >> 1)) & 3;
    gb[j] = (size_t)r * K + qq * 8;
    lb[j] = (j * 128 + (t & ~63)) * 8;
  }

  // frag read offsets (round-5 rotation): row*32 + ((q+(row>>1))&3)*8
  int aoff[4], boff[4];
#pragma unroll
  for (int mi = 0; mi < 4; ++mi) {
    int row = wm * 64 + mi * 16 + r16;
    aoff[mi] = row * 32 + (((q + (row >> 1)) & 3) << 3);
  }
#pragma unroll
  for (int ni = 0; ni < 4; ++ni) {
    int row = ni * 16 + r16;
    boff[ni] = row * 32 + (((q + (row >> 1)) & 3) << 3);
  }

  for (int kt = 0; kt < K / 32; ++kt) {
    int kof = kt * 32;
#pragma unroll
    for (int j = 0; j < 4; ++j) stage16(Abase + ga[j] + kof, &As[la[j]]);
#pragma unroll
    for (int j = 0; j < 2; ++j) stage16(Bbase + gb[j] + kof, &Bs[lb[j]]);
    __syncthreads();
    bf16x8 a[4], b[4];
#pragma unroll
    for (int mi = 0; mi < 4; ++mi) a[mi] = *(const bf16x8*)&As[aoff[mi]];
#pragma unroll
    for (int ni = 0; ni < 4; ++ni) b[ni] = *(const bf16x8*)&Bs[boff[ni]];
#pragma unroll
    for (int mi = 0; mi < 4; ++mi)
#pragma unroll
      for (int ni = 0; ni < 4; ++ni)
        acc[mi][ni] = __builtin_amdgcn_mfma_f32_16x16x32_bf16(a[mi], b[ni], acc[mi][ni], 0, 0, 0);
    __syncthreads();
  }

  // fused epilogue: out = relu(HW - dinv[row]*acc); cols n0..n0+64 (one batch b)
#pragma unroll
  for (int mi = 0; mi < 4; ++mi) {
    int row = m0 + wm * 64 + mi * 16 + q * 4;
    float di[4];
#pragma unroll
    for (int rr = 0; rr < 4; ++rr) di[rr] = dinv[row + rr];
#pragma unroll
    for (int ni = 0; ni < 4; ++ni) {
      int col = n0 + ni * 16 + r16;
      int b_ = col >> 8, o = col & 255;
#pragma unroll
      for (int rr = 0; rr < 4; ++rr) {
        size_t oi = ((size_t)b_ * N_NODES + (row + rr)) * F_DIM + o;
        float u = bf2f(HWb[oi]) - di[rr] * acc[mi][ni][rr];
        Out[oi] = u > 0.f ? u : 0.f;
      }
    }
  }
}

extern "C" void kernel_launch(void* const* d_in, const int* in_sizes, int n_in,
                              void* d_out, int out_size, void* d_ws, size_t ws_size,
                              hipStream_t stream) {
  (void)in_sizes; (void)n_in; (void)out_size; (void)ws_size;
  const float* H = (const float*)d_in[0];
  const float* W = (const float*)d_in[1];
  const float* A = (const float*)d_in[2];
  float* out = (float*)d_out;

  char* ws = (char*)d_ws;
  size_t off = 0;
  auto alloc = [&](size_t bytes) {
    char* p = ws + off;
    off += (bytes + 255) & ~(size_t)255;
    return p;
  };
  float*          Dd   = (float*)alloc((size_t)N_NODES * 4);
  float*          dinv = (float*)alloc((size_t)N_NODES * 4);
  unsigned short* Sb   = (unsigned short*)alloc((size_t)N_NODES * N_NODES * 2);        // 32 MB
  unsigned short* HWb  = (unsigned short*)alloc((size_t)BATCH * N_NODES * F_DIM * 2);  // 16 MB
  unsigned short* Gt   = (unsigned short*)alloc((size_t)BATCH * F_DIM * N_NODES * 2);  // 16 MB
  unsigned short* Wt   = (unsigned short*)alloc((size_t)F_DIM * F_DIM * 2);
  unsigned short* Hb   = (unsigned short*)alloc((size_t)BATCH * N_NODES * F_DIM * 2);  // 16 MB

  hipMemsetAsync(Dd, 0, N_NODES * 4, stream);
  k_pre<<<dim3(64, 64), 256, 0, stream>>>(A, Sb, Dd, (const float4*)H, (ushort4*)Hb, W, Wt);
  k_dinv<<<16, 256, 0, stream>>>(Dd, dinv);
  k_gemm1<<<dim3(2, 256), 256, 0, stream>>>(Hb, Wt, dinv, HWb, Gt);
  k_gemm2<<<1024, 128, 0, stream>>>(Sb, Gt, HWb, dinv, out);
}